// Round 1
// baseline (15539.044 us; speedup 1.0000x reference)
//
#include <hip/hip_runtime.h>
#include <math.h>

// TransformerPolicy forward, fp32 baseline.
// B=32, C=3, HW=224, K=16 -> T=196, E=768, NH=12, dh=64, NB=8, FF=3072
// FLAT=150528, TF=512, NA=4

#define B_    32
#define T_    196
#define E_    768
#define NH_   12
#define DH_   64
#define FF_   3072
#define NB_   8
#define FLAT_ 150528
#define TF2_  1024
#define TF_   512

// ---------------------------------------------------------------- patches
__global__ __launch_bounds__(256) void gather_patches(const float* __restrict__ fov,
                                                      float* __restrict__ P) {
  int idx = blockIdx.x * 256 + threadIdx.x;
  const int total = B_ * T_ * E_;
  if (idx >= total) return;
  int m = idx / E_;   // b*T + t
  int k = idx % E_;   // c*256 + kh*16 + kw
  int b = m / T_, t = m % T_;
  int ph = t / 14, pw = t % 14;
  int c = k >> 8;
  int kh = (k >> 4) & 15;
  int kw = k & 15;
  P[idx] = fov[((b * 3 + c) * 224 + ph * 16 + kh) * 224 + pw * 16 + kw];
}

// conv_w [E,768] row-major (row = out-channel) -> Wt[k][e] for plain A@W GEMM
__global__ __launch_bounds__(256) void transpose768(const float* __restrict__ Win,
                                                    float* __restrict__ Wout) {
  int idx = blockIdx.x * 256 + threadIdx.x;
  if (idx >= E_ * E_) return;
  int k = idx / E_, e = idx % E_;
  Wout[idx] = Win[e * E_ + k];
}

// ---------------------------------------------------------------- GEMM
// C[M,N] = A[M,K] @ W[K,N] (+bias). M%64==0, N%64==0, K%16==0.
// 64x64 tile, 256 threads, 4x4 per thread.
__global__ __launch_bounds__(256) void gemm64(const float* __restrict__ A,
                                              const float* __restrict__ W,
                                              const float* __restrict__ bias,
                                              float* __restrict__ C,
                                              int M, int N, int K) {
  __shared__ float As[16][68];  // [k][m], padded for alignment/banks
  __shared__ float Ws[16][68];  // [k][n]
  const int tid = threadIdx.x;
  const int tx = tid & 15, ty = tid >> 4;
  const int bx = blockIdx.x, by = blockIdx.y;
  const int aRow = tid >> 2;          // 0..63
  const int aCol = (tid & 3) << 2;    // 0,4,8,12
  const int wRow = tid >> 4;          // 0..15
  const int wCol = (tid & 15) << 2;   // 0..60
  const float* Ap = A + (size_t)(by * 64 + aRow) * K + aCol;
  const float* Wp = W + (size_t)wRow * N + bx * 64 + wCol;
  float acc[4][4];
#pragma unroll
  for (int i = 0; i < 4; ++i)
#pragma unroll
    for (int j = 0; j < 4; ++j) acc[i][j] = 0.f;

  for (int k0 = 0; k0 < K; k0 += 16) {
    float4 av = *(const float4*)(Ap + k0);
    float4 wv = *(const float4*)(Wp + (size_t)k0 * N);
    __syncthreads();
    As[aCol + 0][aRow] = av.x;
    As[aCol + 1][aRow] = av.y;
    As[aCol + 2][aRow] = av.z;
    As[aCol + 3][aRow] = av.w;
    *(float4*)&Ws[wRow][wCol] = wv;
    __syncthreads();
#pragma unroll
    for (int kk = 0; kk < 16; ++kk) {
      float4 a = *(const float4*)&As[kk][ty << 2];
      float4 b = *(const float4*)&Ws[kk][tx << 2];
      acc[0][0] += a.x * b.x; acc[0][1] += a.x * b.y; acc[0][2] += a.x * b.z; acc[0][3] += a.x * b.w;
      acc[1][0] += a.y * b.x; acc[1][1] += a.y * b.y; acc[1][2] += a.y * b.z; acc[1][3] += a.y * b.w;
      acc[2][0] += a.z * b.x; acc[2][1] += a.z * b.y; acc[2][2] += a.z * b.z; acc[2][3] += a.z * b.w;
      acc[3][0] += a.w * b.x; acc[3][1] += a.w * b.y; acc[3][2] += a.w * b.z; acc[3][3] += a.w * b.w;
    }
  }
  int row0 = by * 64 + (ty << 2);
  int col0 = bx * 64 + (tx << 2);
#pragma unroll
  for (int i = 0; i < 4; ++i) {
#pragma unroll
    for (int j = 0; j < 4; ++j) {
      float v = acc[i][j];
      if (bias) v += bias[col0 + j];
      C[(size_t)(row0 + i) * N + col0 + j] = v;
    }
  }
}

// ---------------------------------------------------------------- LayerNorm
// out[row] = LN(in[row])*g+b  (optional relu, optional residual add_src)
__global__ __launch_bounds__(256) void ln_kernel(const float* __restrict__ in,
                                                 const float* __restrict__ g,
                                                 const float* __restrict__ bta,
                                                 const float* __restrict__ add_src,
                                                 float* __restrict__ out,
                                                 int R, int relu) {
  __shared__ float rs[256], rs2[256];
  int row = blockIdx.x;
  const float* xr = in + (size_t)row * R;
  float s = 0.f, s2 = 0.f;
  for (int i = threadIdx.x; i < R; i += 256) {
    float v = xr[i];
    s += v;
    s2 += v * v;
  }
  rs[threadIdx.x] = s;
  rs2[threadIdx.x] = s2;
  __syncthreads();
  for (int off = 128; off > 0; off >>= 1) {
    if (threadIdx.x < off) {
      rs[threadIdx.x] += rs[threadIdx.x + off];
      rs2[threadIdx.x] += rs2[threadIdx.x + off];
    }
    __syncthreads();
  }
  float mean = rs[0] / (float)R;
  float var = rs2[0] / (float)R - mean * mean;
  float inv = rsqrtf(var + 1e-5f);
  float* orow = out + (size_t)row * R;
  const float* arow = add_src ? add_src + (size_t)row * R : (const float*)0;
  for (int i = threadIdx.x; i < R; i += 256) {
    float v = (xr[i] - mean) * inv * g[i] + bta[i];
    if (relu) v = fmaxf(v, 0.f);
    if (arow) v += arow[i];
    orow[i] = v;
  }
}

// ---------------------------------------------------------------- attention
// One block per (b,h). Flash-style online softmax; q,o in regs; K/V tiled in LDS.
// x[b,t,h*64+d] += softmax(q k^T / 14) v
__global__ __launch_bounds__(256) void attention_kernel(const float* __restrict__ q,
                                                        const float* __restrict__ k,
                                                        const float* __restrict__ v,
                                                        float* __restrict__ x) {
  __shared__ float Ks[64][65];
  __shared__ float Vs[64][65];
  int b = blockIdx.x / NH_, h = blockIdx.x % NH_;
  int t = threadIdx.x;
  float qr[64];
  float o[64];
  float mx = -1e30f, l = 0.f;
  if (t < T_) {
    const float* qp = q + (size_t)(b * T_ + t) * E_ + h * DH_;
#pragma unroll
    for (int d = 0; d < 64; ++d) {
      qr[d] = qp[d];
      o[d] = 0.f;
    }
  }
  const float scale = 1.0f / 14.0f;  // 1/sqrt(T)
  for (int s0 = 0; s0 < T_; s0 += 64) {
    int sc = T_ - s0;
    if (sc > 64) sc = 64;
    __syncthreads();
    for (int idx = threadIdx.x; idx < sc * 64; idx += 256) {
      int ss = idx >> 6, d = idx & 63;
      size_t gidx = (size_t)(b * T_ + s0 + ss) * E_ + h * DH_ + d;
      Ks[ss][d] = k[gidx];
      Vs[ss][d] = v[gidx];
    }
    __syncthreads();
    if (t < T_) {
      for (int ss = 0; ss < sc; ++ss) {
        float dot = 0.f;
#pragma unroll
        for (int d = 0; d < 64; ++d) dot += qr[d] * Ks[ss][d];
        dot *= scale;
        float mn = fmaxf(mx, dot);
        float alpha = __expf(mx - mn);
        float p = __expf(dot - mn);
        l = l * alpha + p;
        mx = mn;
#pragma unroll
        for (int d = 0; d < 64; ++d) o[d] = o[d] * alpha + p * Vs[ss][d];
      }
    }
  }
  if (t < T_) {
    float inv = 1.0f / l;
    float* xp = x + (size_t)(b * T_ + t) * E_ + h * DH_;
#pragma unroll
    for (int d = 0; d < 64; ++d) xp[d] += o[d] * inv;
  }
}

// ---------------------------------------------------------------- trunk1
// t1[32,1024] (+)= f[32,150528] @ W[150528,1024]; split-K, atomic finalize.
__global__ __launch_bounds__(256) void init_bias_kernel(const float* __restrict__ bias,
                                                        float* __restrict__ outp,
                                                        int M, int N) {
  int idx = blockIdx.x * 256 + threadIdx.x;
  if (idx < M * N) outp[idx] = bias[idx % N];
}

__global__ __launch_bounds__(256) void trunk1_kernel(const float* __restrict__ f,
                                                     const float* __restrict__ W,
                                                     float* __restrict__ t1) {
  __shared__ float fs[32][33];
  int n = blockIdx.x * 256 + threadIdx.x;  // 0..1023
  int k0base = blockIdx.y * 1024;          // 147 slices * 1024 = 150528
  float acc[32];
#pragma unroll
  for (int m = 0; m < 32; ++m) acc[m] = 0.f;
  int mm = threadIdx.x >> 5;  // 0..7
  int kk = threadIdx.x & 31;
  for (int kc = 0; kc < 1024; kc += 32) {
    int k0 = k0base + kc;
    __syncthreads();
#pragma unroll
    for (int r = 0; r < 4; ++r)
      fs[mm + r * 8][kk] = f[(size_t)(mm + r * 8) * FLAT_ + k0 + kk];
    __syncthreads();
#pragma unroll 8
    for (int k2 = 0; k2 < 32; ++k2) {
      float w = W[(size_t)(k0 + k2) * TF2_ + n];
#pragma unroll
      for (int m = 0; m < 32; ++m) acc[m] += fs[m][k2] * w;
    }
  }
#pragma unroll
  for (int m = 0; m < 32; ++m) atomicAdd(&t1[m * TF2_ + n], acc[m]);
}

// ---------------------------------------------------------------- small gemms
// C[m,n] = A[m,:K] @ W[K,N] + bias, one block-row of n per (bx, m=by)
__global__ __launch_bounds__(256) void small_gemm(const float* __restrict__ A,
                                                  const float* __restrict__ W,
                                                  const float* __restrict__ bias,
                                                  float* __restrict__ C,
                                                  int N, int K) {
  int m = blockIdx.y;
  int n = blockIdx.x * 256 + threadIdx.x;
  if (n >= N) return;
  float acc = bias[n];
  const float* ar = A + (size_t)m * K;
  for (int k = 0; k < K; ++k) acc += ar[k] * W[(size_t)k * N + n];
  C[(size_t)m * N + n] = acc;
}

__global__ __launch_bounds__(256) void cat_kernel(const float* __restrict__ cur,
                                                  const float* __restrict__ tgt,
                                                  const float* __restrict__ f,
                                                  float* __restrict__ outp) {
  int idx = blockIdx.x * 256 + threadIdx.x;
  const int total = B_ * 516;
  if (idx >= total) return;
  int m = idx / 516, j = idx % 516;
  float v;
  if (j < 2) v = cur[m * 2 + j];
  else if (j < 4) v = tgt[m * 2 + j - 2];
  else v = f[m * 512 + j - 4];
  outp[idx] = v;
}

__global__ __launch_bounds__(64) void head2_kernel(const float* __restrict__ h1,
                                                   const float* __restrict__ W,
                                                   const float* __restrict__ bias,
                                                   float* __restrict__ outp) {
  int m = blockIdx.x;
  int n = threadIdx.x;
  if (n < 4) {
    float acc = bias[n];
    for (int kk = 0; kk < TF_; ++kk) acc += h1[m * TF_ + kk] * W[kk * 4 + n];
    outp[m * 4 + n] = acc;
  }
}

// ---------------------------------------------------------------- launch
extern "C" void kernel_launch(void* const* d_in, const int* in_sizes, int n_in,
                              void* d_out, int out_size, void* d_ws, size_t ws_size,
                              hipStream_t stream) {
  const float* fov    = (const float*)d_in[0];
  const float* cur    = (const float*)d_in[1];
  const float* tgt    = (const float*)d_in[2];
  const float* conv_w = (const float*)d_in[3];
  const float* conv_b = (const float*)d_in[4];
  const float* ln_in_g = (const float*)d_in[5];
  const float* ln_in_b = (const float*)d_in[6];
  const float* blk_q  = (const float*)d_in[7];
  const float* blk_k  = (const float*)d_in[8];
  const float* blk_v  = (const float*)d_in[9];
  const float* ln1_g  = (const float*)d_in[10];
  const float* ln1_b  = (const float*)d_in[11];
  const float* w1     = (const float*)d_in[12];
  const float* b1     = (const float*)d_in[13];
  const float* ln2_g  = (const float*)d_in[14];
  const float* ln2_b  = (const float*)d_in[15];
  const float* w2     = (const float*)d_in[16];
  const float* b2     = (const float*)d_in[17];
  const float* ln3_g  = (const float*)d_in[18];
  const float* ln3_b  = (const float*)d_in[19];
  const float* img_g  = (const float*)d_in[20];
  const float* img_b  = (const float*)d_in[21];
  const float* t1w    = (const float*)d_in[22];
  const float* t1b    = (const float*)d_in[23];
  const float* tln1_g = (const float*)d_in[24];
  const float* tln1_b = (const float*)d_in[25];
  const float* t2w    = (const float*)d_in[26];
  const float* t2b    = (const float*)d_in[27];
  const float* tln2_g = (const float*)d_in[28];
  const float* tln2_b = (const float*)d_in[29];
  const float* h1w    = (const float*)d_in[30];
  const float* h1b    = (const float*)d_in[31];
  const float* hln_g  = (const float*)d_in[32];
  const float* hln_b  = (const float*)d_in[33];
  const float* h2w    = (const float*)d_in[34];
  const float* h2b    = (const float*)d_in[35];
  float* out = (float*)d_out;

  float* ws = (float*)d_ws;
  size_t off = 0;
  const size_t XE = (size_t)B_ * T_ * E_;  // 4,816,896 floats
  float* P  = ws + off; off += XE;                    // patches, reused as MLP tmp
  float* x  = ws + off; off += XE;                    // residual stream
  float* xn = ws + off; off += XE;                    // LN scratch
  float* qb = ws + off; off += XE;                    // q; reused as f
  float* kb = ws + off; off += XE;
  float* vb = ws + off; off += XE;
  float* hb = ws + off; off += (size_t)B_ * T_ * FF_; // 19.3M floats
  float* Wt = ws + off; off += (size_t)E_ * E_;
  float* t1 = ws + off; off += B_ * TF2_;
  float* t2 = ws + off; off += B_ * TF_;
  float* cb = ws + off; off += B_ * 516;
  float* h1 = ws + off; off += B_ * TF_;
  (void)ws_size; (void)in_sizes; (void)n_in; (void)out_size;

  const int M = B_ * T_;  // 6272
  dim3 blk(256);

  // patch embed
  gather_patches<<<(B_ * T_ * E_ + 255) / 256, blk, 0, stream>>>(fov, P);
  transpose768<<<(E_ * E_ + 255) / 256, blk, 0, stream>>>(conv_w, Wt);
  gemm64<<<dim3(E_ / 64, M / 64), blk, 0, stream>>>(P, Wt, conv_b, x, M, E_, E_);

  for (int i = 0; i < NB_; ++i) {
    ln_kernel<<<M, blk, 0, stream>>>(x, ln_in_g + i * E_, ln_in_b + i * E_, nullptr, xn, E_, 0);
    gemm64<<<dim3(E_ / 64, M / 64), blk, 0, stream>>>(xn, blk_q + (size_t)i * E_ * E_, nullptr, qb, M, E_, E_);
    gemm64<<<dim3(E_ / 64, M / 64), blk, 0, stream>>>(xn, blk_k + (size_t)i * E_ * E_, nullptr, kb, M, E_, E_);
    gemm64<<<dim3(E_ / 64, M / 64), blk, 0, stream>>>(xn, blk_v + (size_t)i * E_ * E_, nullptr, vb, M, E_, E_);
    attention_kernel<<<B_ * NH_, blk, 0, stream>>>(qb, kb, vb, x);
    ln_kernel<<<M, blk, 0, stream>>>(x, ln1_g + i * E_, ln1_b + i * E_, nullptr, xn, E_, 0);
    gemm64<<<dim3(FF_ / 64, M / 64), blk, 0, stream>>>(xn, w1 + (size_t)i * E_ * FF_, b1 + i * FF_, hb, M, FF_, E_);
    ln_kernel<<<M, blk, 0, stream>>>(hb, ln2_g + i * FF_, ln2_b + i * FF_, nullptr, hb, FF_, 1);
    gemm64<<<dim3(E_ / 64, M / 64), blk, 0, stream>>>(hb, w2 + (size_t)i * FF_ * E_, b2 + i * E_, P, M, E_, FF_);
    ln_kernel<<<M, blk, 0, stream>>>(P, ln3_g + i * E_, ln3_b + i * E_, x, x, E_, 0);
  }

  // head: f = LN(x.flat) over 150528 per sample (reuse qb as f)
  ln_kernel<<<B_, blk, 0, stream>>>(x, img_g, img_b, nullptr, qb, FLAT_, 0);
  init_bias_kernel<<<(B_ * TF2_ + 255) / 256, blk, 0, stream>>>(t1b, t1, B_, TF2_);
  trunk1_kernel<<<dim3(4, 147), blk, 0, stream>>>(qb, t1w, t1);
  ln_kernel<<<B_, blk, 0, stream>>>(t1, tln1_g, tln1_b, nullptr, t1, TF2_, 1);
  small_gemm<<<dim3(2, B_), blk, 0, stream>>>(t1, t2w, t2b, t2, TF_, TF2_);
  ln_kernel<<<B_, blk, 0, stream>>>(t2, tln2_g, tln2_b, nullptr, t2, TF_, 1);
  cat_kernel<<<(B_ * 516 + 255) / 256, blk, 0, stream>>>(cur, tgt, t2, cb);
  small_gemm<<<dim3(2, B_), blk, 0, stream>>>(cb, h1w, h1b, h1, TF_, 516);
  ln_kernel<<<B_, blk, 0, stream>>>(h1, hln_g, hln_b, nullptr, h1, TF_, 1);
  head2_kernel<<<B_, dim3(64), 0, stream>>>(h1, h2w, h2b, out);
}

// Round 2
// 7498.422 us; speedup vs baseline: 2.0723x; 2.0723x over previous
//
#include <hip/hip_runtime.h>
#include <math.h>

// TransformerPolicy forward — bf16 MFMA GEMMs (m97 structure), fp32 elsewhere.
// B=32, T=196, E=768, NH=12, dh=64, NB=8, FF=3072, FLAT=150528, TF=512, NA=4

#define B_    32
#define T_    196
#define E_    768
#define NH_   12
#define DH_   64
#define FF_   3072
#define NB_   8
#define FLAT_ 150528
#define TF2_  1024
#define TF_   512
#define QKV_LD 2304   // packed q|k|v output row stride

typedef __attribute__((ext_vector_type(8))) short short8;
typedef __attribute__((ext_vector_type(4))) float float4v;

static __device__ __forceinline__ unsigned short f2bf(float f) {
  unsigned int u = __float_as_uint(f);
  u = u + 0x7fffu + ((u >> 16) & 1u);   // round-to-nearest-even
  return (unsigned short)(u >> 16);
}

// ---------------------------------------------------------------- patches (bf16 out)
__global__ __launch_bounds__(256) void gather_patches(const float* __restrict__ fov,
                                                      unsigned short* __restrict__ P) {
  int idx = blockIdx.x * 256 + threadIdx.x;
  const int total = B_ * T_ * E_;
  if (idx >= total) return;
  int m = idx / E_;
  int k = idx % E_;
  int b = m / T_, t = m % T_;
  int ph = t / 14, pw = t % 14;
  int c = k >> 8;
  int kh = (k >> 4) & 15;
  int kw = k & 15;
  P[idx] = f2bf(fov[((b * 3 + c) * 224 + ph * 16 + kh) * 224 + pw * 16 + kw]);
}

// elementwise fp32 -> bf16
__global__ __launch_bounds__(256) void cvt_bf16(const float* __restrict__ in,
                                                unsigned short* __restrict__ outp, int n) {
  int idx = blockIdx.x * 256 + threadIdx.x;
  if (idx < n) outp[idx] = f2bf(in[idx]);
}

// transpose + convert: in [R][C] fp32 (possibly NB matrices), out [C][R] bf16
__global__ __launch_bounds__(256) void transpose_cvt(const float* __restrict__ in,
                                                     unsigned short* __restrict__ outp,
                                                     int R, int Cc,
                                                     long in_ms, long out_ms) {
  __shared__ float tile[32][33];
  const float* ip = in + (size_t)blockIdx.z * in_ms;
  unsigned short* op = outp + (size_t)blockIdx.z * out_ms;
  int c0 = blockIdx.x * 32, r0 = blockIdx.y * 32;
  int tx = threadIdx.x & 31, ty = threadIdx.x >> 5;  // ty 0..7
#pragma unroll
  for (int i = 0; i < 32; i += 8)
    tile[ty + i][tx] = ip[(size_t)(r0 + ty + i) * Cc + c0 + tx];
  __syncthreads();
#pragma unroll
  for (int i = 0; i < 32; i += 8)
    op[(size_t)(c0 + ty + i) * R + r0 + tx] = f2bf(tile[tx][ty + i]);
}

// ---------------------------------------------------------------- MFMA GEMM
// C[M,N] = A[M,K](bf16) @ Bt[N,K](bf16)^T + bias. 128x128 tile, BK=32, 256 thr.
__global__ __launch_bounds__(256) void gemm_bt_mfma(const unsigned short* __restrict__ A,
                                                    const unsigned short* __restrict__ Bt,
                                                    const float* __restrict__ bias,
                                                    float* __restrict__ C,
                                                    int M, int N, int K) {
  __shared__ unsigned short As[128 * 32];  // [row][k] row-major, 64B rows
  __shared__ unsigned short Bs[128 * 32];
  const int tid = threadIdx.x;
  const int wave = tid >> 6, lane = tid & 63;
  const int wr = wave >> 1, wc = wave & 1;
  const int m0 = blockIdx.y * 128, n0 = blockIdx.x * 128;

  float4v acc[4][4];
#pragma unroll
  for (int i = 0; i < 4; ++i)
#pragma unroll
    for (int j = 0; j < 4; ++j) acc[i][j] = (float4v){0.f, 0.f, 0.f, 0.f};

  // staging slots: slot s = (wave*2+c)*64+lane covers elems s*8..s*8+7
  const int sA = wave * 128 + lane;        // c=0 slot; c=1 slot = sA+64
  const int arow = sA >> 2;                // 0..127 (c=1: +16)
  const int acol = (sA & 3) * 8;
  const unsigned short* Abase = A + (size_t)(m0 + arow) * K + acol;
  const unsigned short* Bbase = Bt + (size_t)(n0 + arow) * K + acol;
  unsigned short* lA = As + wave * 1024;   // bytes: wave*2048; elems wave*1024
  unsigned short* lB = Bs + wave * 1024;

  const int kg = (lane >> 4) * 8;
  const int rsel = lane & 15;

  for (int k0 = 0; k0 < K; k0 += 32) {
    __syncthreads();
    __builtin_amdgcn_global_load_lds(
        (const __attribute__((address_space(1))) unsigned int*)(const void*)(Abase + k0),
        (__attribute__((address_space(3))) unsigned int*)(void*)(lA), 16, 0, 0);
    __builtin_amdgcn_global_load_lds(
        (const __attribute__((address_space(1))) unsigned int*)(const void*)(Abase + (size_t)16 * K + k0),
        (__attribute__((address_space(3))) unsigned int*)(void*)(lA + 512), 16, 0, 0);
    __builtin_amdgcn_global_load_lds(
        (const __attribute__((address_space(1))) unsigned int*)(const void*)(Bbase + k0),
        (__attribute__((address_space(3))) unsigned int*)(void*)(lB), 16, 0, 0);
    __builtin_amdgcn_global_load_lds(
        (const __attribute__((address_space(1))) unsigned int*)(const void*)(Bbase + (size_t)16 * K + k0),
        (__attribute__((address_space(3))) unsigned int*)(void*)(lB + 512), 16, 0, 0);
    asm volatile("s_waitcnt vmcnt(0)" ::: "memory");
    __syncthreads();

    short8 af[4], bf[4];
#pragma unroll
    for (int mi = 0; mi < 4; ++mi)
      af[mi] = *(const short8*)(As + (size_t)(wr * 64 + mi * 16 + rsel) * 32 + kg);
#pragma unroll
    for (int ni = 0; ni < 4; ++ni)
      bf[ni] = *(const short8*)(Bs + (size_t)(wc * 64 + ni * 16 + rsel) * 32 + kg);
#pragma unroll
    for (int mi = 0; mi < 4; ++mi)
#pragma unroll
      for (int ni = 0; ni < 4; ++ni)
        acc[mi][ni] = __builtin_amdgcn_mfma_f32_16x16x32_bf16(af[mi], bf[ni], acc[mi][ni], 0, 0, 0);
  }

  // C/D layout: col = lane&15, row = (lane>>4)*4 + r  [m89/m91 verified]
  const int cr0 = m0 + wr * 64 + (lane >> 4) * 4;
  const int cc0 = n0 + wc * 64 + (lane & 15);
#pragma unroll
  for (int mi = 0; mi < 4; ++mi)
#pragma unroll
    for (int ni = 0; ni < 4; ++ni) {
      int col = cc0 + ni * 16;
      float bv = bias ? bias[col] : 0.f;
#pragma unroll
      for (int r = 0; r < 4; ++r)
        C[(size_t)(cr0 + mi * 16 + r) * N + col] = acc[mi][ni][r] + bv;
    }
}

// ---------------------------------------------------------------- LayerNorm (reg-cached)
// R = CNT*256. Writes fp32 (out32) or bf16 (out16). Optional relu / residual add.
template <int CNT>
__global__ __launch_bounds__(256) void ln_kernel(const float* __restrict__ in,
                                                 const float* __restrict__ g,
                                                 const float* __restrict__ bta,
                                                 const float* __restrict__ add_src,
                                                 float* __restrict__ out32,
                                                 unsigned short* __restrict__ out16,
                                                 int relu) {
  const int R = CNT * 256;
  int row = blockIdx.x;
  const float* xr = in + (size_t)row * R;
  float v[CNT];
  float s = 0.f, s2 = 0.f;
#pragma unroll
  for (int i = 0; i < CNT; ++i) {
    float t = xr[i * 256 + threadIdx.x];
    v[i] = t; s += t; s2 += t * t;
  }
#pragma unroll
  for (int o = 32; o > 0; o >>= 1) { s += __shfl_down(s, o); s2 += __shfl_down(s2, o); }
  __shared__ float rs_[4], rs2_[4];
  int wave = threadIdx.x >> 6, lane = threadIdx.x & 63;
  if (lane == 0) { rs_[wave] = s; rs2_[wave] = s2; }
  __syncthreads();
  s = rs_[0] + rs_[1] + rs_[2] + rs_[3];
  s2 = rs2_[0] + rs2_[1] + rs2_[2] + rs2_[3];
  float mean = s / (float)R;
  float inv = rsqrtf(s2 / (float)R - mean * mean + 1e-5f);
#pragma unroll
  for (int i = 0; i < CNT; ++i) {
    int c = i * 256 + threadIdx.x;
    float t = (v[i] - mean) * inv * g[c] + bta[c];
    if (relu) t = fmaxf(t, 0.f);
    if (add_src) t += add_src[(size_t)row * R + c];
    if (out32) out32[(size_t)row * R + c] = t;
    else out16[(size_t)row * R + c] = f2bf(t);
  }
}

// LN over FLAT per sample (32 rows)
__global__ __launch_bounds__(1024) void ln_big(const float* __restrict__ in,
                                               const float* __restrict__ g,
                                               const float* __restrict__ bta,
                                               float* __restrict__ outp) {
  __shared__ float red[16], red2[16];
  int row = blockIdx.x;
  const float* xr = in + (size_t)row * FLAT_;
  float s = 0.f, s2 = 0.f;
  for (int i = threadIdx.x; i < FLAT_; i += 1024) { float t = xr[i]; s += t; s2 += t * t; }
  for (int o = 32; o > 0; o >>= 1) { s += __shfl_down(s, o); s2 += __shfl_down(s2, o); }
  int wave = threadIdx.x >> 6, lane = threadIdx.x & 63;
  if (lane == 0) { red[wave] = s; red2[wave] = s2; }
  __syncthreads();
  if (threadIdx.x == 0) {
    float a = 0.f, b2 = 0.f;
    for (int i = 0; i < 16; ++i) { a += red[i]; b2 += red2[i]; }
    red[0] = a; red2[0] = b2;
  }
  __syncthreads();
  s = red[0]; s2 = red2[0];
  float mean = s / (float)FLAT_;
  float inv = rsqrtf(s2 / (float)FLAT_ - mean * mean + 1e-5f);
  for (int i = threadIdx.x; i < FLAT_; i += 1024)
    outp[(size_t)row * FLAT_ + i] = (xr[i] - mean) * inv * g[i] + bta[i];
}

// ---------------------------------------------------------------- attention (fp32)
// qkv packed [M, 2304]: q @ +0, k @ +768, v @ +1536. x += softmax(q k^T /14) v
__global__ __launch_bounds__(256) void attention_kernel(const float* __restrict__ qkv,
                                                        float* __restrict__ x) {
  __shared__ float Ks[64][65];
  __shared__ float Vs[64][65];
  int b = blockIdx.x / NH_, h = blockIdx.x % NH_;
  int t = threadIdx.x;
  float qr[64], o[64];
  float mx = -1e30f, l = 0.f;
  if (t < T_) {
    const float* qp = qkv + (size_t)(b * T_ + t) * QKV_LD + h * DH_;
#pragma unroll
    for (int d = 0; d < 64; ++d) { qr[d] = qp[d]; o[d] = 0.f; }
  }
  const float scale = 1.0f / 14.0f;
  for (int s0 = 0; s0 < T_; s0 += 64) {
    int sc = T_ - s0; if (sc > 64) sc = 64;
    __syncthreads();
    for (int idx = threadIdx.x; idx < sc * 64; idx += 256) {
      int ss = idx >> 6, d = idx & 63;
      size_t base = (size_t)(b * T_ + s0 + ss) * QKV_LD + h * DH_ + d;
      Ks[ss][d] = qkv[base + 768];
      Vs[ss][d] = qkv[base + 1536];
    }
    __syncthreads();
    if (t < T_) {
      for (int ss = 0; ss < sc; ++ss) {
        float dot = 0.f;
#pragma unroll
        for (int d = 0; d < 64; ++d) dot += qr[d] * Ks[ss][d];
        dot *= scale;
        float mn = fmaxf(mx, dot);
        float alpha = __expf(mx - mn);
        float p = __expf(dot - mn);
        l = l * alpha + p;
        mx = mn;
#pragma unroll
        for (int d = 0; d < 64; ++d) o[d] = o[d] * alpha + p * Vs[ss][d];
      }
    }
  }
  if (t < T_) {
    float inv = 1.0f / l;
    float* xp = x + (size_t)(b * T_ + t) * E_ + h * DH_;
#pragma unroll
    for (int d = 0; d < 64; ++d) xp[d] += o[d] * inv;
  }
}

// ---------------------------------------------------------------- trunk1
__global__ __launch_bounds__(256) void init_bias_kernel(const float* __restrict__ bias,
                                                        float* __restrict__ outp,
                                                        int M, int N) {
  int idx = blockIdx.x * 256 + threadIdx.x;
  if (idx < M * N) outp[idx] = bias[idx % N];
}

// t1[32,1024] += f[32,150528] @ W[150528,1024]; grid (4 ntile, 294 kslice)
#define TKS_ 512
__global__ __launch_bounds__(256) void trunk1_kernel(const float* __restrict__ f,
                                                     const float* __restrict__ W,
                                                     float* __restrict__ t1) {
  __shared__ float fs[32][33];
  const int tid = threadIdx.x;
  const int nt = tid & 63;   // 64 n-groups of 4
  const int mg = tid >> 6;   // 4 m-groups of 8
  const int n = blockIdx.x * 256 + nt * 4;
  const int k0 = blockIdx.y * TKS_;
  float4 acc[8];
#pragma unroll
  for (int r = 0; r < 8; ++r) acc[r] = make_float4(0.f, 0.f, 0.f, 0.f);
  const int lm = tid >> 3;          // 32 rows, 8 threads/row
  const int lk = (tid & 7) * 4;
  for (int kc = 0; kc < TKS_; kc += 32) {
    __syncthreads();
    *(float4*)&fs[lm][lk] = *(const float4*)&f[(size_t)lm * FLAT_ + k0 + kc + lk];
    __syncthreads();
#pragma unroll 8
    for (int k2 = 0; k2 < 32; ++k2) {
      float4 w4 = *(const float4*)&W[(size_t)(k0 + kc + k2) * TF2_ + n];
#pragma unroll
      for (int r = 0; r < 8; ++r) {
        float fv = fs[mg * 8 + r][k2];
        acc[r].x += fv * w4.x; acc[r].y += fv * w4.y;
        acc[r].z += fv * w4.z; acc[r].w += fv * w4.w;
      }
    }
  }
#pragma unroll
  for (int r = 0; r < 8; ++r) {
    atomicAdd(&t1[(mg * 8 + r) * TF2_ + n + 0], acc[r].x);
    atomicAdd(&t1[(mg * 8 + r) * TF2_ + n + 1], acc[r].y);
    atomicAdd(&t1[(mg * 8 + r) * TF2_ + n + 2], acc[r].z);
    atomicAdd(&t1[(mg * 8 + r) * TF2_ + n + 3], acc[r].w);
  }
}

// ---------------------------------------------------------------- small gemms / head
__global__ __launch_bounds__(256) void small_gemm(const float* __restrict__ A,
                                                  const float* __restrict__ W,
                                                  const float* __restrict__ bias,
                                                  float* __restrict__ C,
                                                  int N, int K) {
  int m = blockIdx.y;
  int n = blockIdx.x * 256 + threadIdx.x;
  if (n >= N) return;
  float acc = bias[n];
  const float* ar = A + (size_t)m * K;
  for (int k = 0; k < K; ++k) acc += ar[k] * W[(size_t)k * N + n];
  C[(size_t)m * N + n] = acc;
}

__global__ __launch_bounds__(256) void cat_kernel(const float* __restrict__ cur,
                                                  const float* __restrict__ tgt,
                                                  const float* __restrict__ f,
                                                  float* __restrict__ outp) {
  int idx = blockIdx.x * 256 + threadIdx.x;
  const int total = B_ * 516;
  if (idx >= total) return;
  int m = idx / 516, j = idx % 516;
  float v;
  if (j < 2) v = cur[m * 2 + j];
  else if (j < 4) v = tgt[m * 2 + j - 2];
  else v = f[m * 512 + j - 4];
  outp[idx] = v;
}

__global__ __launch_bounds__(64) void head2_kernel(const float* __restrict__ h1,
                                                   const float* __restrict__ W,
                                                   const float* __restrict__ bias,
                                                   float* __restrict__ outp) {
  int m = blockIdx.x;
  int n = threadIdx.x;
  if (n < 4) {
    float acc = bias[n];
    for (int kk = 0; kk < TF_; ++kk) acc += h1[m * TF_ + kk] * W[kk * 4 + n];
    outp[m * 4 + n] = acc;
  }
}

// ---------------------------------------------------------------- launch
extern "C" void kernel_launch(void* const* d_in, const int* in_sizes, int n_in,
                              void* d_out, int out_size, void* d_ws, size_t ws_size,
                              hipStream_t stream) {
  const float* fov    = (const float*)d_in[0];
  const float* cur    = (const float*)d_in[1];
  const float* tgt    = (const float*)d_in[2];
  const float* conv_w = (const float*)d_in[3];
  const float* conv_b = (const float*)d_in[4];
  const float* ln_in_g = (const float*)d_in[5];
  const float* ln_in_b = (const float*)d_in[6];
  const float* blk_q  = (const float*)d_in[7];
  const float* blk_k  = (const float*)d_in[8];
  const float* blk_v  = (const float*)d_in[9];
  const float* ln1_g  = (const float*)d_in[10];
  const float* ln1_b  = (const float*)d_in[11];
  const float* w1     = (const float*)d_in[12];
  const float* b1     = (const float*)d_in[13];
  const float* ln2_g  = (const float*)d_in[14];
  const float* ln2_b  = (const float*)d_in[15];
  const float* w2     = (const float*)d_in[16];
  const float* b2     = (const float*)d_in[17];
  const float* ln3_g  = (const float*)d_in[18];
  const float* ln3_b  = (const float*)d_in[19];
  const float* img_g  = (const float*)d_in[20];
  const float* img_b  = (const float*)d_in[21];
  const float* t1w    = (const float*)d_in[22];
  const float* t1b    = (const float*)d_in[23];
  const float* tln1_g = (const float*)d_in[24];
  const float* tln1_b = (const float*)d_in[25];
  const float* t2w    = (const float*)d_in[26];
  const float* t2b    = (const float*)d_in[27];
  const float* tln2_g = (const float*)d_in[28];
  const float* tln2_b = (const float*)d_in[29];
  const float* h1w    = (const float*)d_in[30];
  const float* h1b    = (const float*)d_in[31];
  const float* hln_g  = (const float*)d_in[32];
  const float* hln_b  = (const float*)d_in[33];
  const float* h2w    = (const float*)d_in[34];
  const float* h2b    = (const float*)d_in[35];
  float* out = (float*)d_out;

  float* ws = (float*)d_ws;
  size_t off = 0;
  const size_t XE = (size_t)B_ * T_ * E_;      // 4,816,896
  const size_t XF = (size_t)B_ * T_ * FF_;     // 19,267,584
  float* x    = ws + off; off += XE;                   // residual (fp32)
  float* qkvb = ws + off; off += (size_t)B_ * T_ * QKV_LD;  // qkv / w2-out / f
  float* hb   = ws + off; off += XF;                   // w1 out (fp32)
  unsigned short* xn_b = (unsigned short*)(ws + off); off += XE / 2;       // LN out bf16 / patches
  unsigned short* hb_b = (unsigned short*)(ws + off); off += XF / 2;       // ln2 out bf16
  unsigned short* cwb  = (unsigned short*)(ws + off); off += (size_t)E_ * E_ / 2;
  unsigned short* wqkvb = (unsigned short*)(ws + off); off += (size_t)NB_ * QKV_LD * E_ / 2;
  unsigned short* w1b  = (unsigned short*)(ws + off); off += (size_t)NB_ * E_ * FF_ / 2;
  unsigned short* w2b  = (unsigned short*)(ws + off); off += (size_t)NB_ * E_ * FF_ / 2;
  float* t1 = ws + off; off += B_ * TF2_;
  float* t2 = ws + off; off += B_ * TF_;
  float* cb = ws + off; off += B_ * 516;
  float* h1 = ws + off; off += B_ * TF_;
  (void)ws_size; (void)in_sizes; (void)n_in; (void)out_size;

  const int M = B_ * T_;  // 6272
  dim3 blk(256);

  // ---- weight conversion (bf16, transposed to [N][K]) ----
  cvt_bf16<<<(E_ * E_ + 255) / 256, blk, 0, stream>>>(conv_w, cwb, E_ * E_);  // already [E][K]
  // blk_q/k/v [E,768] -> wqkvb rows 0..767 / 768..1535 / 1536..2303
  transpose_cvt<<<dim3(24, 24, NB_), blk, 0, stream>>>(blk_q, wqkvb + 0 * E_ * E_,
                                                       E_, E_, (long)E_ * E_, (long)QKV_LD * E_);
  transpose_cvt<<<dim3(24, 24, NB_), blk, 0, stream>>>(blk_k, wqkvb + 1 * E_ * E_,
                                                       E_, E_, (long)E_ * E_, (long)QKV_LD * E_);
  transpose_cvt<<<dim3(24, 24, NB_), blk, 0, stream>>>(blk_v, wqkvb + 2 * E_ * E_,
                                                       E_, E_, (long)E_ * E_, (long)QKV_LD * E_);
  transpose_cvt<<<dim3(96, 24, NB_), blk, 0, stream>>>(w1, w1b, E_, FF_,
                                                       (long)E_ * FF_, (long)E_ * FF_);
  transpose_cvt<<<dim3(24, 96, NB_), blk, 0, stream>>>(w2, w2b, FF_, E_,
                                                       (long)E_ * FF_, (long)E_ * FF_);

  // ---- patch embed ----
  gather_patches<<<(B_ * T_ * E_ + 255) / 256, blk, 0, stream>>>(fov, xn_b);
  gemm_bt_mfma<<<dim3(E_ / 128, M / 128), blk, 0, stream>>>(xn_b, cwb, conv_b, x, M, E_, E_);

  // ---- transformer blocks ----
  for (int i = 0; i < NB_; ++i) {
    ln_kernel<3><<<M, blk, 0, stream>>>(x, ln_in_g + i * E_, ln_in_b + i * E_,
                                        nullptr, nullptr, xn_b, 0);
    gemm_bt_mfma<<<dim3(QKV_LD / 128, M / 128), blk, 0, stream>>>(
        xn_b, wqkvb + (size_t)i * QKV_LD * E_, nullptr, qkvb, M, QKV_LD, E_);
    attention_kernel<<<B_ * NH_, blk, 0, stream>>>(qkvb, x);
    ln_kernel<3><<<M, blk, 0, stream>>>(x, ln1_g + i * E_, ln1_b + i * E_,
                                        nullptr, nullptr, xn_b, 0);
    gemm_bt_mfma<<<dim3(FF_ / 128, M / 128), blk, 0, stream>>>(
        xn_b, w1b + (size_t)i * E_ * FF_, b1 + i * FF_, hb, M, FF_, E_);
    ln_kernel<12><<<M, blk, 0, stream>>>(hb, ln2_g + i * FF_, ln2_b + i * FF_,
                                         nullptr, nullptr, hb_b, 1);
    gemm_bt_mfma<<<dim3(E_ / 128, M / 128), blk, 0, stream>>>(
        hb_b, w2b + (size_t)i * E_ * FF_, b2 + i * E_, qkvb, M, E_, FF_);
    ln_kernel<3><<<M, blk, 0, stream>>>(qkvb, ln3_g + i * E_, ln3_b + i * E_,
                                        x, x, nullptr, 0);
  }

  // ---- head ----
  float* f = qkvb;  // 19.3 MB region reuse
  ln_big<<<B_, dim3(1024), 0, stream>>>(x, img_g, img_b, f);
  init_bias_kernel<<<(B_ * TF2_ + 255) / 256, blk, 0, stream>>>(t1b, t1, B_, TF2_);
  trunk1_kernel<<<dim3(TF2_ / 256, FLAT_ / TKS_), blk, 0, stream>>>(f, t1w, t1);
  ln_kernel<4><<<B_, blk, 0, stream>>>(t1, tln1_g, tln1_b, nullptr, t1, nullptr, 1);
  small_gemm<<<dim3(2, B_), blk, 0, stream>>>(t1, t2w, t2b, t2, TF_, TF2_);
  ln_kernel<2><<<B_, blk, 0, stream>>>(t2, tln2_g, tln2_b, nullptr, t2, nullptr, 1);
  cat_kernel<<<(B_ * 516 + 255) / 256, blk, 0, stream>>>(cur, tgt, t2, cb);
  small_gemm<<<dim3(2, B_), blk, 0, stream>>>(cb, h1w, h1b, h1, TF_, 516);
  ln_kernel<2><<<B_, blk, 0, stream>>>(h1, hln_g, hln_b, nullptr, h1, nullptr, 1);
  head2_kernel<<<B_, dim3(64), 0, stream>>>(h1, h2w, h2b, out);
}

// Round 3
// 4280.138 us; speedup vs baseline: 3.6305x; 1.7519x over previous
//
#include <hip/hip_runtime.h>
#include <math.h>

// TransformerPolicy forward — bf16 MFMA GEMMs + MFMA flash attention.
// B=32, T=196, E=768, NH=12, dh=64, NB=8, FF=3072, FLAT=150528, TF=512, NA=4

#define B_    32
#define T_    196
#define E_    768
#define NH_   12
#define DH_   64
#define FF_   3072
#define NB_   8
#define FLAT_ 150528
#define TF2_  1024
#define TF_   512
#define QKV_LD 2304   // packed q|k|v output row stride

typedef __attribute__((ext_vector_type(8))) short short8;
typedef __attribute__((ext_vector_type(4))) float float4v;

static __device__ __forceinline__ unsigned short f2bf(float f) {
  unsigned int u = __float_as_uint(f);
  u = u + 0x7fffu + ((u >> 16) & 1u);   // round-to-nearest-even
  return (unsigned short)(u >> 16);
}

// ---------------------------------------------------------------- patches (bf16 out)
__global__ __launch_bounds__(256) void gather_patches(const float* __restrict__ fov,
                                                      unsigned short* __restrict__ P) {
  int idx = blockIdx.x * 256 + threadIdx.x;
  const int total = B_ * T_ * E_;
  if (idx >= total) return;
  int m = idx / E_;
  int k = idx % E_;
  int b = m / T_, t = m % T_;
  int ph = t / 14, pw = t % 14;
  int c = k >> 8;
  int kh = (k >> 4) & 15;
  int kw = k & 15;
  P[idx] = f2bf(fov[((b * 3 + c) * 224 + ph * 16 + kh) * 224 + pw * 16 + kw]);
}

// elementwise fp32 -> bf16
__global__ __launch_bounds__(256) void cvt_bf16(const float* __restrict__ in,
                                                unsigned short* __restrict__ outp, int n) {
  int idx = blockIdx.x * 256 + threadIdx.x;
  if (idx < n) outp[idx] = f2bf(in[idx]);
}

// transpose + convert: in [R][C] fp32 (possibly NB matrices), out [C][R] bf16
__global__ __launch_bounds__(256) void transpose_cvt(const float* __restrict__ in,
                                                     unsigned short* __restrict__ outp,
                                                     int R, int Cc,
                                                     long in_ms, long out_ms) {
  __shared__ float tile[32][33];
  const float* ip = in + (size_t)blockIdx.z * in_ms;
  unsigned short* op = outp + (size_t)blockIdx.z * out_ms;
  int c0 = blockIdx.x * 32, r0 = blockIdx.y * 32;
  int tx = threadIdx.x & 31, ty = threadIdx.x >> 5;  // ty 0..7
#pragma unroll
  for (int i = 0; i < 32; i += 8)
    tile[ty + i][tx] = ip[(size_t)(r0 + ty + i) * Cc + c0 + tx];
  __syncthreads();
#pragma unroll
  for (int i = 0; i < 32; i += 8)
    op[(size_t)(c0 + ty + i) * R + r0 + tx] = f2bf(tile[tx][ty + i]);
}

// ---------------------------------------------------------------- MFMA GEMM
// C[M,N] = A[M,K](bf16) @ Bt[N,K](bf16)^T + bias. 128x128 tile, BK=32, 256 thr.
template <typename OutT>
__global__ __launch_bounds__(256) void gemm_bt_mfma(const unsigned short* __restrict__ A,
                                                    const unsigned short* __restrict__ Bt,
                                                    const float* __restrict__ bias,
                                                    OutT* __restrict__ C,
                                                    int M, int N, int K) {
  __shared__ unsigned short As[128 * 32];  // [row][k] row-major, 64B rows
  __shared__ unsigned short Bs[128 * 32];
  const int tid = threadIdx.x;
  const int wave = tid >> 6, lane = tid & 63;
  const int wr = wave >> 1, wc = wave & 1;
  const int m0 = blockIdx.y * 128, n0 = blockIdx.x * 128;

  float4v acc[4][4];
#pragma unroll
  for (int i = 0; i < 4; ++i)
#pragma unroll
    for (int j = 0; j < 4; ++j) acc[i][j] = (float4v){0.f, 0.f, 0.f, 0.f};

  const int sA = wave * 128 + lane;
  const int arow = sA >> 2;
  const int acol = (sA & 3) * 8;
  const unsigned short* Abase = A + (size_t)(m0 + arow) * K + acol;
  const unsigned short* Bbase = Bt + (size_t)(n0 + arow) * K + acol;
  unsigned short* lA = As + wave * 1024;
  unsigned short* lB = Bs + wave * 1024;

  const int kg = (lane >> 4) * 8;
  const int rsel = lane & 15;

  for (int k0 = 0; k0 < K; k0 += 32) {
    __syncthreads();
    __builtin_amdgcn_global_load_lds(
        (const __attribute__((address_space(1))) unsigned int*)(const void*)(Abase + k0),
        (__attribute__((address_space(3))) unsigned int*)(void*)(lA), 16, 0, 0);
    __builtin_amdgcn_global_load_lds(
        (const __attribute__((address_space(1))) unsigned int*)(const void*)(Abase + (size_t)16 * K + k0),
        (__attribute__((address_space(3))) unsigned int*)(void*)(lA + 512), 16, 0, 0);
    __builtin_amdgcn_global_load_lds(
        (const __attribute__((address_space(1))) unsigned int*)(const void*)(Bbase + k0),
        (__attribute__((address_space(3))) unsigned int*)(void*)(lB), 16, 0, 0);
    __builtin_amdgcn_global_load_lds(
        (const __attribute__((address_space(1))) unsigned int*)(const void*)(Bbase + (size_t)16 * K + k0),
        (__attribute__((address_space(3))) unsigned int*)(void*)(lB + 512), 16, 0, 0);
    asm volatile("s_waitcnt vmcnt(0)" ::: "memory");
    __syncthreads();

    short8 af[4], bf[4];
#pragma unroll
    for (int mi = 0; mi < 4; ++mi)
      af[mi] = *(const short8*)(As + (size_t)(wr * 64 + mi * 16 + rsel) * 32 + kg);
#pragma unroll
    for (int ni = 0; ni < 4; ++ni)
      bf[ni] = *(const short8*)(Bs + (size_t)(wc * 64 + ni * 16 + rsel) * 32 + kg);
#pragma unroll
    for (int mi = 0; mi < 4; ++mi)
#pragma unroll
      for (int ni = 0; ni < 4; ++ni)
        acc[mi][ni] = __builtin_amdgcn_mfma_f32_16x16x32_bf16(af[mi], bf[ni], acc[mi][ni], 0, 0, 0);
  }

  // C/D layout: col = lane&15, row = (lane>>4)*4 + r
  const int cr0 = m0 + wr * 64 + (lane >> 4) * 4;
  const int cc0 = n0 + wc * 64 + (lane & 15);
#pragma unroll
  for (int mi = 0; mi < 4; ++mi)
#pragma unroll
    for (int ni = 0; ni < 4; ++ni) {
      int col = cc0 + ni * 16;
      float bv = bias ? bias[col] : 0.f;
#pragma unroll
      for (int r = 0; r < 4; ++r) {
        float v = acc[mi][ni][r] + bv;
        if constexpr (sizeof(OutT) == 2)
          C[(size_t)(cr0 + mi * 16 + r) * N + col] = f2bf(v);
        else
          C[(size_t)(cr0 + mi * 16 + r) * N + col] = v;
      }
    }
}

// ---------------------------------------------------------------- LayerNorm (reg-cached)
template <int CNT>
__global__ __launch_bounds__(256) void ln_kernel(const float* __restrict__ in,
                                                 const float* __restrict__ g,
                                                 const float* __restrict__ bta,
                                                 const float* __restrict__ add_src,
                                                 float* __restrict__ out32,
                                                 unsigned short* __restrict__ out16,
                                                 int relu) {
  const int R = CNT * 256;
  int row = blockIdx.x;
  const float* xr = in + (size_t)row * R;
  float v[CNT];
  float s = 0.f, s2 = 0.f;
#pragma unroll
  for (int i = 0; i < CNT; ++i) {
    float t = xr[i * 256 + threadIdx.x];
    v[i] = t; s += t; s2 += t * t;
  }
#pragma unroll
  for (int o = 32; o > 0; o >>= 1) { s += __shfl_down(s, o); s2 += __shfl_down(s2, o); }
  __shared__ float rs_[4], rs2_[4];
  int wave = threadIdx.x >> 6, lane = threadIdx.x & 63;
  if (lane == 0) { rs_[wave] = s; rs2_[wave] = s2; }
  __syncthreads();
  s = rs_[0] + rs_[1] + rs_[2] + rs_[3];
  s2 = rs2_[0] + rs2_[1] + rs2_[2] + rs2_[3];
  float mean = s / (float)R;
  float inv = rsqrtf(s2 / (float)R - mean * mean + 1e-5f);
#pragma unroll
  for (int i = 0; i < CNT; ++i) {
    int c = i * 256 + threadIdx.x;
    float t = (v[i] - mean) * inv * g[c] + bta[c];
    if (relu) t = fmaxf(t, 0.f);
    if (add_src) t += add_src[(size_t)row * R + c];
    if (out32) out32[(size_t)row * R + c] = t;
    else out16[(size_t)row * R + c] = f2bf(t);
  }
}

// LN over FLAT per sample (32 rows)
__global__ __launch_bounds__(1024) void ln_big(const float* __restrict__ in,
                                               const float* __restrict__ g,
                                               const float* __restrict__ bta,
                                               float* __restrict__ outp) {
  __shared__ float red[16], red2[16];
  int row = blockIdx.x;
  const float* xr = in + (size_t)row * FLAT_;
  float s = 0.f, s2 = 0.f;
  for (int i = threadIdx.x; i < FLAT_; i += 1024) { float t = xr[i]; s += t; s2 += t * t; }
  for (int o = 32; o > 0; o >>= 1) { s += __shfl_down(s, o); s2 += __shfl_down(s2, o); }
  int wave = threadIdx.x >> 6, lane = threadIdx.x & 63;
  if (lane == 0) { red[wave] = s; red2[wave] = s2; }
  __syncthreads();
  if (threadIdx.x == 0) {
    float a = 0.f, b2 = 0.f;
    for (int i = 0; i < 16; ++i) { a += red[i]; b2 += red2[i]; }
    red[0] = a; red2[0] = b2;
  }
  __syncthreads();
  s = red[0]; s2 = red2[0];
  float mean = s / (float)FLAT_;
  float inv = rsqrtf(s2 / (float)FLAT_ - mean * mean + 1e-5f);
  for (int i = threadIdx.x; i < FLAT_; i += 1024)
    outp[(size_t)row * FLAT_ + i] = (xr[i] - mean) * inv * g[i] + bta[i];
}

// ---------------------------------------------------------------- attention (MFMA flash)
// qkv bf16 [B*T][2304]: q@0, k@+768, v@+1536. x[b,t,h*64+d] += softmax(qk^T/14) v.
// Block = (qchunk 0..3, h, b). 4 waves; wave owns 16 q-rows (chunk*64+wave*16..).
// K padded to 224 cols (masked). S computed fully per wave (14 N-tiles of C-frags),
// exact softmax in regs, P -> LDS (aliases K region) -> A-frags for PV.
__global__ __launch_bounds__(256) void attention_mfma(const unsigned short* __restrict__ qkv,
                                                      float* __restrict__ x) {
  __shared__ unsigned short smem[28672];     // 57,344 B
  unsigned short* Kh = smem;                 // [2 half][224 s][32 k]
  unsigned short* Vt = smem + 14336;         // [7 chunk][64 d][32 s]
  unsigned short* Ps = smem;                 // [4 wave][7 chunk][16 m][32 k] (aliases Kh)
  const int chunk = blockIdx.x, h = blockIdx.y, b = blockIdx.z;
  const int tid = threadIdx.x, wave = tid >> 6, lane = tid & 63;
  const int quad = lane >> 4, rsel = lane & 15;

  // ---- stage K (row-major halves) and V (transposed [d][s]) ----
  for (int task = tid; task < 1792; task += 256) {
    int s = task >> 3, seg = task & 7;       // seg: 8-col group
    short8 kv = {0, 0, 0, 0, 0, 0, 0, 0};
    short8 vv = {0, 0, 0, 0, 0, 0, 0, 0};
    if (s < 196) {
      const unsigned short* gp = qkv + (size_t)(b * 196 + s) * 2304 + h * 64 + seg * 8;
      kv = *(const short8*)(gp + 768);
      vv = *(const short8*)(gp + 1536);
    }
    *(short8*)(Kh + (seg >> 2) * 7168 + s * 32 + (seg & 3) * 8) = kv;
    int c = s >> 5, sw = s & 31;
#pragma unroll
    for (int j = 0; j < 8; ++j)
      Vt[c * 2048 + (seg * 8 + j) * 32 + sw] = (unsigned short)vv[j];
  }

  // Q A-frags direct from global (A[m=lane&15][k=quad*8+j]); clamp padded rows
  int qrow = chunk * 64 + wave * 16 + rsel;
  int qc = qrow < 196 ? qrow : 195;
  const unsigned short* qp = qkv + (size_t)(b * 196 + qc) * 2304 + h * 64 + quad * 8;
  short8 a0 = *(const short8*)qp;
  short8 a1 = *(const short8*)(qp + 32);

  __syncthreads();

  // ---- S = Q K^T ----
  float4v S[14];
#pragma unroll
  for (int ni = 0; ni < 14; ++ni) S[ni] = (float4v){0.f, 0.f, 0.f, 0.f};
#pragma unroll
  for (int ni = 0; ni < 14; ++ni) {
    const unsigned short* kb = Kh + (ni * 16 + rsel) * 32 + quad * 8;
    S[ni] = __builtin_amdgcn_mfma_f32_16x16x32_bf16(a0, *(const short8*)kb, S[ni], 0, 0, 0);
    S[ni] = __builtin_amdgcn_mfma_f32_16x16x32_bf16(a1, *(const short8*)(kb + 7168), S[ni], 0, 0, 0);
  }

  // ---- softmax (exact, per row t = quad*4 + r) ----
  const float scale = 1.0f / 14.0f;
  float mr[4] = {-1e30f, -1e30f, -1e30f, -1e30f};
#pragma unroll
  for (int ni = 0; ni < 14; ++ni) {
    int col = ni * 16 + rsel;
#pragma unroll
    for (int r = 0; r < 4; ++r) {
      float v = (col < 196) ? S[ni][r] * scale : -1e30f;
      S[ni][r] = v;
      mr[r] = fmaxf(mr[r], v);
    }
  }
#pragma unroll
  for (int o = 1; o < 16; o <<= 1) {
#pragma unroll
    for (int r = 0; r < 4; ++r) mr[r] = fmaxf(mr[r], __shfl_xor(mr[r], o));
  }
  float lr[4] = {0.f, 0.f, 0.f, 0.f};
#pragma unroll
  for (int ni = 0; ni < 14; ++ni) {
#pragma unroll
    for (int r = 0; r < 4; ++r) {
      float p = __expf(S[ni][r] - mr[r]);
      S[ni][r] = p;
      lr[r] += p;
    }
  }
#pragma unroll
  for (int o = 1; o < 16; o <<= 1) {
#pragma unroll
    for (int r = 0; r < 4; ++r) lr[r] += __shfl_xor(lr[r], o);
  }

  // ---- P (C-layout) -> LDS -> A-layout ----
  __syncthreads();  // all waves done reading Kh
#pragma unroll
  for (int ni = 0; ni < 14; ++ni) {
    int c = ni >> 1, cw = (ni & 1) * 16 + rsel;
#pragma unroll
    for (int r = 0; r < 4; ++r)
      Ps[wave * 3584 + c * 512 + (quad * 4 + r) * 32 + cw] = f2bf(S[ni][r]);
  }
  __syncthreads();

  // ---- O = P V ----
  float4v O[4];
#pragma unroll
  for (int nd = 0; nd < 4; ++nd) O[nd] = (float4v){0.f, 0.f, 0.f, 0.f};
#pragma unroll
  for (int c = 0; c < 7; ++c) {
    short8 pa = *(const short8*)(Ps + wave * 3584 + c * 512 + rsel * 32 + quad * 8);
#pragma unroll
    for (int nd = 0; nd < 4; ++nd) {
      short8 vb = *(const short8*)(Vt + c * 2048 + (nd * 16 + rsel) * 32 + quad * 8);
      O[nd] = __builtin_amdgcn_mfma_f32_16x16x32_bf16(pa, vb, O[nd], 0, 0, 0);
    }
  }

  // ---- x += O / l (disjoint (t,h) slices: race-free) ----
  int t0 = chunk * 64 + wave * 16 + quad * 4;
  float invl[4];
#pragma unroll
  for (int r = 0; r < 4; ++r) invl[r] = 1.0f / lr[r];
#pragma unroll
  for (int r = 0; r < 4; ++r) {
    int t = t0 + r;
    if (t < 196) {
      float* xp = x + (size_t)(b * 196 + t) * 768 + h * 64 + rsel;
#pragma unroll
      for (int nd = 0; nd < 4; ++nd) xp[nd * 16] += O[nd][r] * invl[r];
    }
  }
}

// ---------------------------------------------------------------- trunk1
__global__ __launch_bounds__(256) void init_bias_kernel(const float* __restrict__ bias,
                                                        float* __restrict__ outp,
                                                        int M, int N) {
  int idx = blockIdx.x * 256 + threadIdx.x;
  if (idx < M * N) outp[idx] = bias[idx % N];
}

#define TKS_ 512
__global__ __launch_bounds__(256) void trunk1_kernel(const float* __restrict__ f,
                                                     const float* __restrict__ W,
                                                     float* __restrict__ t1) {
  __shared__ float fs[32][33];
  const int tid = threadIdx.x;
  const int nt = tid & 63;
  const int mg = tid >> 6;
  const int n = blockIdx.x * 256 + nt * 4;
  const int k0 = blockIdx.y * TKS_;
  float4 acc[8];
#pragma unroll
  for (int r = 0; r < 8; ++r) acc[r] = make_float4(0.f, 0.f, 0.f, 0.f);
  const int lm = tid >> 3;
  const int lk = (tid & 7) * 4;
  for (int kc = 0; kc < TKS_; kc += 32) {
    __syncthreads();
    *(float4*)&fs[lm][lk] = *(const float4*)&f[(size_t)lm * FLAT_ + k0 + kc + lk];
    __syncthreads();
#pragma unroll 8
    for (int k2 = 0; k2 < 32; ++k2) {
      float4 w4 = *(const float4*)&W[(size_t)(k0 + kc + k2) * TF2_ + n];
#pragma unroll
      for (int r = 0; r < 8; ++r) {
        float fv = fs[mg * 8 + r][k2];
        acc[r].x += fv * w4.x; acc[r].y += fv * w4.y;
        acc[r].z += fv * w4.z; acc[r].w += fv * w4.w;
      }
    }
  }
#pragma unroll
  for (int r = 0; r < 8; ++r) {
    atomicAdd(&t1[(mg * 8 + r) * TF2_ + n + 0], acc[r].x);
    atomicAdd(&t1[(mg * 8 + r) * TF2_ + n + 1], acc[r].y);
    atomicAdd(&t1[(mg * 8 + r) * TF2_ + n + 2], acc[r].z);
    atomicAdd(&t1[(mg * 8 + r) * TF2_ + n + 3], acc[r].w);
  }
}

// ---------------------------------------------------------------- small gemms / head
__global__ __launch_bounds__(256) void small_gemm(const float* __restrict__ A,
                                                  const float* __restrict__ W,
                                                  const float* __restrict__ bias,
                                                  float* __restrict__ C,
                                                  int N, int K) {
  int m = blockIdx.y;
  int n = blockIdx.x * 256 + threadIdx.x;
  if (n >= N) return;
  float acc = bias[n];
  const float* ar = A + (size_t)m * K;
  for (int k = 0; k < K; ++k) acc += ar[k] * W[(size_t)k * N + n];
  C[(size_t)m * N + n] = acc;
}

__global__ __launch_bounds__(256) void cat_kernel(const float* __restrict__ cur,
                                                  const float* __restrict__ tgt,
                                                  const float* __restrict__ f,
                                                  float* __restrict__ outp) {
  int idx = blockIdx.x * 256 + threadIdx.x;
  const int total = B_ * 516;
  if (idx >= total) return;
  int m = idx / 516, j = idx % 516;
  float v;
  if (j < 2) v = cur[m * 2 + j];
  else if (j < 4) v = tgt[m * 2 + j - 2];
  else v = f[m * 512 + j - 4];
  outp[idx] = v;
}

__global__ __launch_bounds__(64) void head2_kernel(const float* __restrict__ h1,
                                                   const float* __restrict__ W,
                                                   const float* __restrict__ bias,
                                                   float* __restrict__ outp) {
  int m = blockIdx.x;
  int n = threadIdx.x;
  if (n < 4) {
    float acc = bias[n];
    for (int kk = 0; kk < TF_; ++kk) acc += h1[m * TF_ + kk] * W[kk * 4 + n];
    outp[m * 4 + n] = acc;
  }
}

// ---------------------------------------------------------------- launch
extern "C" void kernel_launch(void* const* d_in, const int* in_sizes, int n_in,
                              void* d_out, int out_size, void* d_ws, size_t ws_size,
                              hipStream_t stream) {
  const float* fov    = (const float*)d_in[0];
  const float* cur    = (const float*)d_in[1];
  const float* tgt    = (const float*)d_in[2];
  const float* conv_w = (const float*)d_in[3];
  const float* conv_b = (const float*)d_in[4];
  const float* ln_in_g = (const float*)d_in[5];
  const float* ln_in_b = (const float*)d_in[6];
  const float* blk_q  = (const float*)d_in[7];
  const float* blk_k  = (const float*)d_in[8];
  const float* blk_v  = (const float*)d_in[9];
  const float* ln1_g  = (const float*)d_in[10];
  const float* ln1_b  = (const float*)d_in[11];
  const float* w1     = (const float*)d_in[12];
  const float* b1     = (const float*)d_in[13];
  const float* ln2_g  = (const float*)d_in[14];
  const float* ln2_b  = (const float*)d_in[15];
  const float* w2     = (const float*)d_in[16];
  const float* b2     = (const float*)d_in[17];
  const float* ln3_g  = (const float*)d_in[18];
  const float* ln3_b  = (const float*)d_in[19];
  const float* img_g  = (const float*)d_in[20];
  const float* img_b  = (const float*)d_in[21];
  const float* t1w    = (const float*)d_in[22];
  const float* t1b    = (const float*)d_in[23];
  const float* tln1_g = (const float*)d_in[24];
  const float* tln1_b = (const float*)d_in[25];
  const float* t2w    = (const float*)d_in[26];
  const float* t2b    = (const float*)d_in[27];
  const float* tln2_g = (const float*)d_in[28];
  const float* tln2_b = (const float*)d_in[29];
  const float* h1w    = (const float*)d_in[30];
  const float* h1b    = (const float*)d_in[31];
  const float* hln_g  = (const float*)d_in[32];
  const float* hln_b  = (const float*)d_in[33];
  const float* h2w    = (const float*)d_in[34];
  const float* h2b    = (const float*)d_in[35];
  float* out = (float*)d_out;

  float* ws = (float*)d_ws;
  size_t off = 0;
  const size_t XE = (size_t)B_ * T_ * E_;      // 4,816,896
  const size_t XF = (size_t)B_ * T_ * FF_;     // 19,267,584
  float* x    = ws + off; off += XE;                   // residual (fp32)
  float* tmp  = ws + off; off += XE;                   // w2-out fp32 / f
  float* hb   = ws + off; off += XF;                   // w1 out (fp32)
  unsigned short* xn_b = (unsigned short*)(ws + off); off += XE / 2;   // LN out bf16 / patches
  unsigned short* hb_b = (unsigned short*)(ws + off); off += XF / 2;   // ln2 out bf16
  unsigned short* qkv_bf = (unsigned short*)(ws + off); off += (size_t)B_ * T_ * QKV_LD / 2;
  unsigned short* cwb  = (unsigned short*)(ws + off); off += (size_t)E_ * E_ / 2;
  unsigned short* wqkvb = (unsigned short*)(ws + off); off += (size_t)NB_ * QKV_LD * E_ / 2;
  unsigned short* w1b  = (unsigned short*)(ws + off); off += (size_t)NB_ * E_ * FF_ / 2;
  unsigned short* w2b  = (unsigned short*)(ws + off); off += (size_t)NB_ * E_ * FF_ / 2;
  float* t1 = ws + off; off += B_ * TF2_;
  float* t2 = ws + off; off += B_ * TF_;
  float* cb = ws + off; off += B_ * 516;
  float* h1 = ws + off; off += B_ * TF_;
  (void)ws_size; (void)in_sizes; (void)n_in; (void)out_size;

  const int M = B_ * T_;  // 6272
  dim3 blk(256);

  // ---- weight conversion (bf16, transposed to [N][K]) ----
  cvt_bf16<<<(E_ * E_ + 255) / 256, blk, 0, stream>>>(conv_w, cwb, E_ * E_);
  transpose_cvt<<<dim3(24, 24, NB_), blk, 0, stream>>>(blk_q, wqkvb + 0 * E_ * E_,
                                                       E_, E_, (long)E_ * E_, (long)QKV_LD * E_);
  transpose_cvt<<<dim3(24, 24, NB_), blk, 0, stream>>>(blk_k, wqkvb + 1 * E_ * E_,
                                                       E_, E_, (long)E_ * E_, (long)QKV_LD * E_);
  transpose_cvt<<<dim3(24, 24, NB_), blk, 0, stream>>>(blk_v, wqkvb + 2 * E_ * E_,
                                                       E_, E_, (long)E_ * E_, (long)QKV_LD * E_);
  transpose_cvt<<<dim3(96, 24, NB_), blk, 0, stream>>>(w1, w1b, E_, FF_,
                                                       (long)E_ * FF_, (long)E_ * FF_);
  transpose_cvt<<<dim3(24, 96, NB_), blk, 0, stream>>>(w2, w2b, FF_, E_,
                                                       (long)E_ * FF_, (long)E_ * FF_);

  // ---- patch embed ----
  gather_patches<<<(B_ * T_ * E_ + 255) / 256, blk, 0, stream>>>(fov, xn_b);
  gemm_bt_mfma<float><<<dim3(E_ / 128, M / 128), blk, 0, stream>>>(xn_b, cwb, conv_b, x, M, E_, E_);

  // ---- transformer blocks ----
  for (int i = 0; i < NB_; ++i) {
    ln_kernel<3><<<M, blk, 0, stream>>>(x, ln_in_g + i * E_, ln_in_b + i * E_,
                                        nullptr, nullptr, xn_b, 0);
    gemm_bt_mfma<unsigned short><<<dim3(QKV_LD / 128, M / 128), blk, 0, stream>>>(
        xn_b, wqkvb + (size_t)i * QKV_LD * E_, nullptr, qkv_bf, M, QKV_LD, E_);
    attention_mfma<<<dim3(4, NH_, B_), blk, 0, stream>>>(qkv_bf, x);
    ln_kernel<3><<<M, blk, 0, stream>>>(x, ln1_g + i * E_, ln1_b + i * E_,
                                        nullptr, nullptr, xn_b, 0);
    gemm_bt_mfma<float><<<dim3(FF_ / 128, M / 128), blk, 0, stream>>>(
        xn_b, w1b + (size_t)i * E_ * FF_, b1 + i * FF_, hb, M, FF_, E_);
    ln_kernel<12><<<M, blk, 0, stream>>>(hb, ln2_g + i * FF_, ln2_b + i * FF_,
                                         nullptr, nullptr, hb_b, 1);
    gemm_bt_mfma<float><<<dim3(E_ / 128, M / 128), blk, 0, stream>>>(
        hb_b, w2b + (size_t)i * E_ * FF_, b2 + i * E_, tmp, M, E_, FF_);
    ln_kernel<3><<<M, blk, 0, stream>>>(tmp, ln3_g + i * E_, ln3_b + i * E_,
                                        x, x, nullptr, 0);
  }

  // ---- head ----
  float* f = tmp;
  ln_big<<<B_, dim3(1024), 0, stream>>>(x, img_g, img_b, f);
  init_bias_kernel<<<(B_ * TF2_ + 255) / 256, blk, 0, stream>>>(t1b, t1, B_, TF2_);
  trunk1_kernel<<<dim3(TF2_ / 256, FLAT_ / TKS_), blk, 0, stream>>>(f, t1w, t1);
  ln_kernel<4><<<B_, blk, 0, stream>>>(t1, tln1_g, tln1_b, nullptr, t1, nullptr, 1);
  small_gemm<<<dim3(2, B_), blk, 0, stream>>>(t1, t2w, t2b, t2, TF_, TF2_);
  ln_kernel<2><<<B_, blk, 0, stream>>>(t2, tln2_g, tln2_b, nullptr, t2, nullptr, 1);
  cat_kernel<<<(B_ * 516 + 255) / 256, blk, 0, stream>>>(cur, tgt, t2, cb);
  small_gemm<<<dim3(2, B_), blk, 0, stream>>>(cb, h1w, h1b, h1, TF_, 516);
  ln_kernel<2><<<B_, blk, 0, stream>>>(h1, hln_g, hln_b, nullptr, h1, nullptr, 1);
  head2_kernel<<<B_, dim3(64), 0, stream>>>(h1, h2w, h2b, out);
}